// Round 2
// baseline (1394.316 us; speedup 1.0000x reference)
//
#include <hip/hip_runtime.h>
#include <hip/hip_bf16.h>
#include <hip/hip_cooperative_groups.h>
#include <cstdint>

namespace cg = cooperative_groups;

typedef __attribute__((ext_vector_type(8))) short short8;
typedef __attribute__((ext_vector_type(4))) float floatx4;

#define HIDDEN 128
#define NOUT 256

// ===========================================================================
// FUSED FRONT (cooperative): zero+prep | hist | scan x3 | fill | gather
// in ONE persistent kernel with grid.sync() between phases.
// Theory: round-1 showed ~130us/dispatch spacing under rocprof and a 3x gap
// between modeled kernel work (~200us) and measured 630us -> dispatch/drain
// overhead bound. 10 dispatches -> 2.
// ===========================================================================
__global__ __launch_bounds__(256, 4) void fused_front(
    const float* __restrict__ x, const float* __restrict__ rbf,
    const int* __restrict__ idx, const float* __restrict__ Wrbf,
    const float* __restrict__ Wd, const float* __restrict__ Ws,
    __hip_bfloat16* __restrict__ WdT, __hip_bfloat16* __restrict__ WsT,
    int* __restrict__ cnt, int* __restrict__ offsets, int* __restrict__ cursor,
    int* __restrict__ edge_ids, int* __restrict__ blocksum,
    int* __restrict__ blockbase, __hip_bfloat16* __restrict__ hacc,
    int E, int M, int nb)
{
    cg::grid_group grid = cg::this_grid();
    int t = threadIdx.x;
    int gtid = blockIdx.x * 256 + t;
    int gsz = gridDim.x * 256;

    __shared__ int wsum[4];
    __shared__ int wtot[4];

    // ---- P0: zero cnt + weight transpose/convert ----
    for (int p = gtid; p < M; p += gsz) cnt[p] = 0;
    for (int p = gtid; p < 256 * 128; p += gsz) {
        int n = p >> 7, k = p & 127;
        WdT[p] = __float2bfloat16(Wd[k * 256 + n]);
    }
    for (int p = gtid; p < 3 * 256 * 256; p += gsz) {
        int l = p >> 16, rem = p & 65535, n = rem >> 8, k = rem & 255;
        WsT[p] = __float2bfloat16(Ws[l * 65536 + k * 256 + n]);
    }
    grid.sync();

    // ---- P1: histogram ----
    for (int e = gtid; e < E; e += gsz) atomicAdd(&cnt[idx[e]], 1);
    grid.sync();

    // ---- P2: per-1024-chunk sums ----
    for (int c = blockIdx.x; c < nb; c += gridDim.x) {
        int base = c * 1024;
        int s = 0;
#pragma unroll
        for (int j = 0; j < 4; ++j) {
            int p = base + t * 4 + j;
            if (p < M) s += cnt[p];
        }
#pragma unroll
        for (int d = 32; d > 0; d >>= 1) s += __shfl_down(s, d);
        if ((t & 63) == 0) wsum[t >> 6] = s;
        __syncthreads();
        if (t == 0) blocksum[c] = wsum[0] + wsum[1] + wsum[2] + wsum[3];
        __syncthreads();
    }
    grid.sync();

    // ---- P3: single-wave exclusive scan of chunk sums (block 0) ----
    if (blockIdx.x == 0 && t < 64) {
        int lane = t;
        int carry = 0;
        for (int base = 0; base < nb; base += 64) {
            int v = (base + lane < nb) ? blocksum[base + lane] : 0;
            int incl = v;
#pragma unroll
            for (int d = 1; d < 64; d <<= 1) {
                int u = __shfl_up(incl, d);
                if (lane >= d) incl += u;
            }
            if (base + lane < nb) blockbase[base + lane] = carry + incl - v;
            carry += __shfl(incl, 63);
        }
        if (lane == 0) offsets[M] = carry;
    }
    grid.sync();

    // ---- P4: per-chunk offset fill ----
    {
        int lane = t & 63, wv = t >> 6;
        for (int c = blockIdx.x; c < nb; c += gridDim.x) {
            int base = c * 1024;
            int v[4];
            int s = 0;
#pragma unroll
            for (int j = 0; j < 4; ++j) {
                int p = base + t * 4 + j;
                v[j] = (p < M) ? cnt[p] : 0;
                s += v[j];
            }
            int incl = s;
#pragma unroll
            for (int d = 1; d < 64; d <<= 1) {
                int u = __shfl_up(incl, d);
                if (lane >= d) incl += u;
            }
            if (lane == 63) wtot[wv] = incl;
            __syncthreads();
            int wbase = 0;
            for (int j = 0; j < wv; ++j) wbase += wtot[j];
            int start = blockbase[c] + wbase + incl - s;
#pragma unroll
            for (int j = 0; j < 4; ++j) {
                int p = base + t * 4 + j;
                if (p < M) { offsets[p] = start; cursor[p] = start; }
                start += v[j];
            }
            __syncthreads();
        }
    }
    grid.sync();

    // ---- P5: stable-ish fill of edge lists ----
    for (int e = gtid; e < E; e += gsz) {
        int pos = atomicAdd(&cursor[idx[e]], 1);
        edge_ids[pos] = e;
    }
    grid.sync();

    // ---- P6: gather — one wave per node, lane owns 2 hidden channels ----
    {
        int wave = t >> 6, lane = t & 63;
        int wgid = blockIdx.x * 4 + wave;
        int nwaves = gridDim.x * 4;
        int c0 = lane * 2;
        float w0[6], w1[6];
#pragma unroll
        for (int r = 0; r < 6; ++r) {
            w0[r] = Wrbf[r * HIDDEN + c0];
            w1[r] = Wrbf[r * HIDDEN + c0 + 1];
        }
        for (int n = wgid; n < M; n += nwaves) {
            int s = offsets[n], eend = offsets[n + 1];
            float a0 = 0.f, a1 = 0.f;
            for (int p = s; p < eend; p += 64) {
                int nbk = eend - p;
                if (nbk > 64) nbk = 64;
                int eid = (p + lane < eend) ? edge_ids[p + lane] : 0;
                int j = 0;
                for (; j + 4 <= nbk; j += 4) {
#pragma unroll
                    for (int u = 0; u < 4; ++u) {
                        int e = __builtin_amdgcn_readlane(eid, j + u);
                        const float* rb = rbf + (long)e * 6;
                        float2 xv = *(const float2*)&x[(long)e * HIDDEN + c0];
                        float p0 = 0.f, p1 = 0.f;
#pragma unroll
                        for (int r = 0; r < 6; ++r) {
                            float rv = rb[r];
                            p0 += rv * w0[r];
                            p1 += rv * w1[r];
                        }
                        a0 += p0 * xv.x;
                        a1 += p1 * xv.y;
                    }
                }
                for (; j < nbk; ++j) {
                    int e = __builtin_amdgcn_readlane(eid, j);
                    const float* rb = rbf + (long)e * 6;
                    float2 xv = *(const float2*)&x[(long)e * HIDDEN + c0];
                    float p0 = 0.f, p1 = 0.f;
#pragma unroll
                    for (int r = 0; r < 6; ++r) {
                        float rv = rb[r];
                        p0 += rv * w0[r];
                        p1 += rv * w1[r];
                    }
                    a0 += p0 * xv.x;
                    a1 += p1 * xv.y;
                }
            }
            __hip_bfloat162 pk;
            pk.x = __float2bfloat16(a0);
            pk.y = __float2bfloat16(a1);
            *(__hip_bfloat162*)&hacc[(long)n * HIDDEN + c0] = pk;
        }
    }
}

// ===========================================================================
// Fallback path kernels (used only if cooperative launch is rejected)
// ===========================================================================
__global__ __launch_bounds__(256) void prep_weights(
    const float* __restrict__ Wd, const float* __restrict__ Ws,
    __hip_bfloat16* __restrict__ WdT, __hip_bfloat16* __restrict__ WsT)
{
    int tid = blockIdx.x * 256 + threadIdx.x;
    if (tid < 256 * 128) {
        int n = tid >> 7, k = tid & 127;
        WdT[tid] = __float2bfloat16(Wd[k * 256 + n]);
    }
    int tid2 = tid - 256 * 128;
    if (tid2 >= 0 && tid2 < 3 * 256 * 256) {
        int l = tid2 >> 16;
        int rem = tid2 & 65535;
        int n = rem >> 8, k = rem & 255;
        WsT[tid2] = __float2bfloat16(Ws[l * 65536 + k * 256 + n]);
    }
}

__global__ __launch_bounds__(256) void hist_k(
    const int* __restrict__ idx, int* __restrict__ cnt, int E)
{
    int e = blockIdx.x * 256 + threadIdx.x;
    if (e < E) atomicAdd(&cnt[idx[e]], 1);
}

__global__ __launch_bounds__(256) void scan_blocksum_k(
    const int* __restrict__ cnt, int* __restrict__ blocksum, int M)
{
    int base = blockIdx.x * 1024;
    int t = threadIdx.x;
    int s = 0;
#pragma unroll
    for (int j = 0; j < 4; ++j) {
        int p = base + t * 4 + j;
        if (p < M) s += cnt[p];
    }
#pragma unroll
    for (int d = 32; d > 0; d >>= 1) s += __shfl_down(s, d);
    __shared__ int wsum[4];
    if ((t & 63) == 0) wsum[t >> 6] = s;
    __syncthreads();
    if (t == 0) blocksum[blockIdx.x] = wsum[0] + wsum[1] + wsum[2] + wsum[3];
}

__global__ __launch_bounds__(64) void scan_base_k(
    const int* __restrict__ blocksum, int* __restrict__ blockbase,
    int* __restrict__ offsets, int nb, int M)
{
    int lane = threadIdx.x;
    int carry = 0;
    for (int base = 0; base < nb; base += 64) {
        int v = (base + lane < nb) ? blocksum[base + lane] : 0;
        int incl = v;
#pragma unroll
        for (int d = 1; d < 64; d <<= 1) {
            int u = __shfl_up(incl, d);
            if (lane >= d) incl += u;
        }
        if (base + lane < nb) blockbase[base + lane] = carry + incl - v;
        carry += __shfl(incl, 63);
    }
    if (lane == 0) offsets[M] = carry;
}

__global__ __launch_bounds__(256) void scan_offsets_k(
    const int* __restrict__ cnt, const int* __restrict__ blockbase,
    int* __restrict__ offsets, int* __restrict__ cursor, int M)
{
    int base = blockIdx.x * 1024;
    int t = threadIdx.x, lane = t & 63, wv = t >> 6;
    int v[4];
    int s = 0;
#pragma unroll
    for (int j = 0; j < 4; ++j) {
        int p = base + t * 4 + j;
        v[j] = (p < M) ? cnt[p] : 0;
        s += v[j];
    }
    int incl = s;
#pragma unroll
    for (int d = 1; d < 64; d <<= 1) {
        int u = __shfl_up(incl, d);
        if (lane >= d) incl += u;
    }
    __shared__ int wtot[4];
    if (lane == 63) wtot[wv] = incl;
    __syncthreads();
    int wbase = 0;
    for (int j = 0; j < wv; ++j) wbase += wtot[j];
    int start = blockbase[blockIdx.x] + wbase + incl - s;
#pragma unroll
    for (int j = 0; j < 4; ++j) {
        int p = base + t * 4 + j;
        if (p < M) { offsets[p] = start; cursor[p] = start; }
        start += v[j];
    }
}

__global__ __launch_bounds__(256) void fill_k(
    const int* __restrict__ idx, int* __restrict__ cursor,
    int* __restrict__ edge_ids, int E)
{
    int e = blockIdx.x * 256 + threadIdx.x;
    if (e < E) {
        int pos = atomicAdd(&cursor[idx[e]], 1);
        edge_ids[pos] = e;
    }
}

__global__ __launch_bounds__(256) void gather_k(
    const float* __restrict__ x, const float* __restrict__ rbf,
    const float* __restrict__ Wrbf, const int* __restrict__ offsets,
    const int* __restrict__ edge_ids, __hip_bfloat16* __restrict__ hacc, int M)
{
    int t = threadIdx.x;
    int wave = t >> 6, lane = t & 63;
    int n = blockIdx.x * 4 + wave;
    if (n >= M) return;
    int c0 = lane * 2;
    float w0[6], w1[6];
#pragma unroll
    for (int r = 0; r < 6; ++r) {
        w0[r] = Wrbf[r * HIDDEN + c0];
        w1[r] = Wrbf[r * HIDDEN + c0 + 1];
    }
    int s = offsets[n], eend = offsets[n + 1];
    float a0 = 0.f, a1 = 0.f;
    for (int p = s; p < eend; p += 64) {
        int nbk = eend - p;
        if (nbk > 64) nbk = 64;
        int eid = (p + lane < eend) ? edge_ids[p + lane] : 0;
        for (int j = 0; j < nbk; ++j) {
            int e = __builtin_amdgcn_readlane(eid, j);
            const float* rb = rbf + (long)e * 6;
            float2 xv = *(const float2*)&x[(long)e * HIDDEN + c0];
            float p0 = 0.f, p1 = 0.f;
#pragma unroll
            for (int r = 0; r < 6; ++r) {
                float rv = rb[r];
                p0 += rv * w0[r];
                p1 += rv * w1[r];
            }
            a0 += p0 * xv.x;
            a1 += p1 * xv.y;
        }
    }
    __hip_bfloat162 pk;
    pk.x = __float2bfloat16(a0);
    pk.y = __float2bfloat16(a1);
    *(__hip_bfloat162*)&hacc[(long)n * HIDDEN + c0] = pk;
}

// ===========================================================================
// Fused MLP (unchanged from round 1 — passed, global-B register prefetch,
// LDS = Al only 33.8KB, barriers 8/block)
// ===========================================================================
__global__ __launch_bounds__(256, 3) void mlp_fused(
    const __hip_bfloat16* __restrict__ hacc, const __hip_bfloat16* __restrict__ WdT,
    const __hip_bfloat16* __restrict__ WsT, const float* __restrict__ bs,
    float* __restrict__ out, int M)
{
    __shared__ __hip_bfloat16 Al[64][264];   // 256 cols + 8 pad

    int t = threadIdx.x;
    int lane = t & 63, w = t >> 6;
    int q = lane >> 4, r16 = lane & 15;
    int m0 = blockIdx.x * 64;

#pragma unroll
    for (int it = 0; it < 4; ++it) {
        int idx = it * 256 + t;
        int row = idx >> 4;
        int col = (idx & 15) * 8;
        int gr = m0 + row; if (gr >= M) gr = M - 1;
        *(short8*)&Al[row][col] = *(const short8*)&hacc[(long)gr * HIDDEN + col];
    }
    __syncthreads();

    for (int layer = 0; layer < 4; ++layer) {
        const int K = (layer == 0) ? 128 : 256;
        const __hip_bfloat16* BT = (layer == 0) ? WdT : WsT + (layer - 1) * 65536;
        const __hip_bfloat16* Brow = BT + (long)(w * 64 + r16) * K;

        floatx4 acc[4][4] = {};
        short8 bcur[4], bnxt[4];
#pragma unroll
        for (int nt = 0; nt < 4; ++nt)
            bcur[nt] = *(const short8*)&Brow[(long)nt * 16 * K + q * 8];

        for (int kk = 0; kk < K; kk += 32) {
            short8 af[4];
#pragma unroll
            for (int mt = 0; mt < 4; ++mt)
                af[mt] = *(const short8*)&Al[mt * 16 + r16][kk + q * 8];
            int kn = kk + 32;
            if (kn < K) {
#pragma unroll
                for (int nt = 0; nt < 4; ++nt)
                    bnxt[nt] = *(const short8*)&Brow[(long)nt * 16 * K + kn + q * 8];
            }
#pragma unroll
            for (int mt = 0; mt < 4; ++mt)
#pragma unroll
                for (int nt = 0; nt < 4; ++nt)
                    acc[mt][nt] = __builtin_amdgcn_mfma_f32_16x16x32_bf16(
                        af[mt], bcur[nt], acc[mt][nt], 0, 0, 0);
#pragma unroll
            for (int nt = 0; nt < 4; ++nt) bcur[nt] = bnxt[nt];
        }

        if (layer < 3) {
            __syncthreads();
            const float* bias = (layer == 0) ? nullptr : bs + (layer - 1) * 256;
#pragma unroll
            for (int mt = 0; mt < 4; ++mt) {
#pragma unroll
                for (int rr = 0; rr < 4; ++rr) {
                    int row = mt * 16 + q * 4 + rr;
#pragma unroll
                    for (int nt = 0; nt < 4; ++nt) {
                        int col = w * 64 + nt * 16 + r16;
                        float v = acc[mt][nt][rr];
                        if (layer > 0) { v += bias[col]; v = v / (1.f + __expf(-v)); }
                        Al[row][col] = __float2bfloat16(v);
                    }
                }
            }
            __syncthreads();
        } else {
            const float* bias = bs + 2 * 256;
#pragma unroll
            for (int mt = 0; mt < 4; ++mt) {
#pragma unroll
                for (int rr = 0; rr < 4; ++rr) {
                    int row = m0 + mt * 16 + q * 4 + rr;
                    if (row < M) {
#pragma unroll
                        for (int nt = 0; nt < 4; ++nt) {
                            int col = w * 64 + nt * 16 + r16;
                            float v = acc[mt][nt][rr] + bias[col];
                            v = v / (1.f + __expf(-v));
                            out[(long)row * NOUT + col] = v;
                        }
                    }
                }
            }
        }
    }
}

// ---------------------------------------------------------------------------
extern "C" void kernel_launch(void* const* d_in, const int* in_sizes, int n_in,
                              void* d_out, int out_size, void* d_ws, size_t ws_size,
                              hipStream_t stream)
{
    const float* x    = (const float*)d_in[0];
    const float* rbf  = (const float*)d_in[1];
    const int*   idx  = (const int*)d_in[2];
    const float* Wrbf = (const float*)d_in[3];
    const float* Wd   = (const float*)d_in[4];
    const float* Ws   = (const float*)d_in[5];
    const float* bs   = (const float*)d_in[6];

    int E = in_sizes[0] / HIDDEN;
    int M = out_size / NOUT;         // num_nodes
    int nb = (M + 1023) / 1024;

    char* ws = (char*)d_ws;
    __hip_bfloat16* hacc = (__hip_bfloat16*)ws;                  // M*128 bf16 (reserve fp32 size)
    size_t off = (size_t)M * HIDDEN * sizeof(float);
    __hip_bfloat16* WdT = (__hip_bfloat16*)(ws + off); off += 256 * 128 * 2;
    __hip_bfloat16* WsT = (__hip_bfloat16*)(ws + off); off += 3 * 256 * 256 * 2;
    int* cnt       = (int*)(ws + off); off += (size_t)M * 4;
    int* offsets   = (int*)(ws + off); off += (size_t)(M + 1) * 4;
    int* cursor    = (int*)(ws + off); off += (size_t)M * 4;
    int* edge_ids  = (int*)(ws + off); off += (size_t)E * 4;
    int* blocksum  = (int*)(ws + off); off += (size_t)nb * 4;
    int* blockbase = (int*)(ws + off); off += (size_t)nb * 4;

    // Cooperative front kernel: size grid to full residency.
    static int occ = -1;
    if (occ < 0) {
        if (hipOccupancyMaxActiveBlocksPerMultiprocessor(&occ, fused_front, 256, 0)
            != hipSuccess || occ < 1) occ = 0;
    }

    bool coop_ok = false;
    if (occ >= 1) {
        int grid = occ * 256;            // 256 CUs on MI355X
        if (grid > 2048) grid = 2048;
        void* kargs[] = {
            (void*)&x, (void*)&rbf, (void*)&idx, (void*)&Wrbf,
            (void*)&Wd, (void*)&Ws, (void*)&WdT, (void*)&WsT,
            (void*)&cnt, (void*)&offsets, (void*)&cursor, (void*)&edge_ids,
            (void*)&blocksum, (void*)&blockbase, (void*)&hacc,
            (void*)&E, (void*)&M, (void*)&nb };
        hipError_t err = hipLaunchCooperativeKernel(
            (void*)fused_front, dim3(grid), dim3(256), kargs, 0, stream);
        coop_ok = (err == hipSuccess);
    }

    if (!coop_ok) {
        // fallback: original 8-dispatch pipeline
        hipMemsetAsync(cnt, 0, (size_t)M * sizeof(int), stream);
        prep_weights<<<(256 * 128 + 3 * 256 * 256 + 255) / 256, 256, 0, stream>>>(Wd, Ws, WdT, WsT);
        hist_k<<<(E + 255) / 256, 256, 0, stream>>>(idx, cnt, E);
        scan_blocksum_k<<<nb, 256, 0, stream>>>(cnt, blocksum, M);
        scan_base_k<<<1, 64, 0, stream>>>(blocksum, blockbase, offsets, nb, M);
        scan_offsets_k<<<nb, 256, 0, stream>>>(cnt, blockbase, offsets, cursor, M);
        fill_k<<<(E + 255) / 256, 256, 0, stream>>>(idx, cursor, edge_ids, E);
        gather_k<<<(M + 3) / 4, 256, 0, stream>>>(x, rbf, Wrbf, offsets, edge_ids, hacc, M);
    }

    mlp_fused<<<(M + 63) / 64, 256, 0, stream>>>(hacc, WdT, WsT, bs, (float*)d_out, M);
}

// Round 4
// 941.267 us; speedup vs baseline: 1.4813x; 1.4813x over previous
//
#include <hip/hip_runtime.h>
#include <hip/hip_bf16.h>
#include <cstdint>

typedef __attribute__((ext_vector_type(8))) short short8;
typedef __attribute__((ext_vector_type(4))) float floatx4;

#define HIDDEN 128
#define NOUT 256

// ---------------------------------------------------------------------------
// One-time weight convert + transpose to bf16.
// WdT[n][k] = W_down[k][n] (256x128); WsT[l][n][k] = Ws[l][k][n] (3x256x256)
// ---------------------------------------------------------------------------
__global__ __launch_bounds__(256) void prep_weights(
    const float* __restrict__ Wd, const float* __restrict__ Ws,
    __hip_bfloat16* __restrict__ WdT, __hip_bfloat16* __restrict__ WsT)
{
    int tid = blockIdx.x * 256 + threadIdx.x;
    if (tid < 256 * 128) {
        int n = tid >> 7, k = tid & 127;
        WdT[tid] = __float2bfloat16(Wd[k * 256 + n]);
    }
    int tid2 = tid - 256 * 128;
    if (tid2 >= 0 && tid2 < 3 * 256 * 256) {
        int l = tid2 >> 16;
        int rem = tid2 & 65535;
        int n = rem >> 8, k = rem & 255;
        WsT[tid2] = __float2bfloat16(Ws[l * 65536 + k * 256 + n]);
    }
}

// ---------------------------------------------------------------------------
// Scatter v1: replaces {hist, scan x3, fill, gather} (6 dispatches) with ONE
// streaming pass over edges. Per edge: gate = (rbf@Wrbf)*x, then fp32
// atomicAdd into hacc[node]. Atomics are fire-and-forget (result unused ->
// global_atomic_add_f32 with no wait); contention avg 12 edges/node.
// Wave layout: lane owns 2 hidden channels; wave processes a contiguous run
// of edges, 4 at a time (4 independent 512B x-row reads in flight).
// ---------------------------------------------------------------------------
__global__ __launch_bounds__(256) void scatter_k(
    const float* __restrict__ x, const float* __restrict__ rbf,
    const int* __restrict__ idx, const float* __restrict__ Wrbf,
    float* __restrict__ hacc, int E)
{
    int t = threadIdx.x;
    int lane = t & 63;
    int wave = (blockIdx.x * 256 + t) >> 6;       // global wave id
    int nwaves = gridDim.x * 4;
    int c0 = lane * 2;

    float w0[6], w1[6];
#pragma unroll
    for (int r = 0; r < 6; ++r) {
        w0[r] = Wrbf[r * HIDDEN + c0];
        w1[r] = Wrbf[r * HIDDEN + c0 + 1];
    }

    // contiguous chunk per wave, rounded to 4
    int epw = ((E + nwaves - 1) / nwaves + 3) & ~3;
    int e0 = wave * epw;
    int e1 = e0 + epw; if (e1 > E) e1 = E;
    if (e0 >= E) return;

    int e = e0;
    for (; e + 4 <= e1; e += 4) {
        int nd[4];
        float2 xv[4];
        float rbv[4][6];
#pragma unroll
        for (int u = 0; u < 4; ++u) {
            int ee = e + u;
            nd[u] = idx[ee];                                   // wave-uniform
            xv[u] = *(const float2*)&x[(long)ee * HIDDEN + c0]; // coalesced 512B
            const float* rb = rbf + (long)ee * 6;               // wave-uniform
#pragma unroll
            for (int r = 0; r < 6; ++r) rbv[u][r] = rb[r];
        }
#pragma unroll
        for (int u = 0; u < 4; ++u) {
            float p0 = 0.f, p1 = 0.f;
#pragma unroll
            for (int r = 0; r < 6; ++r) {
                p0 += rbv[u][r] * w0[r];
                p1 += rbv[u][r] * w1[r];
            }
            float* dst = &hacc[(long)nd[u] * HIDDEN + c0];
            atomicAdd(dst,     p0 * xv[u].x);
            atomicAdd(dst + 1, p1 * xv[u].y);
        }
    }
    for (; e < e1; ++e) {                                      // tail
        int node = idx[e];
        float2 xv = *(const float2*)&x[(long)e * HIDDEN + c0];
        const float* rb = rbf + (long)e * 6;
        float p0 = 0.f, p1 = 0.f;
#pragma unroll
        for (int r = 0; r < 6; ++r) {
            float rv = rb[r];
            p0 += rv * w0[r];
            p1 += rv * w1[r];
        }
        float* dst = &hacc[(long)node * HIDDEN + c0];
        atomicAdd(dst,     p0 * xv.x);
        atomicAdd(dst + 1, p1 * xv.y);
    }
}

// ---------------------------------------------------------------------------
// Fused MLP: down-proj + 3 SiLU layers in ONE kernel. Block = 64 rows.
// B operand global->register with 1-deep prefetch (weights L2-hot, 512 KB
// total re-read by all blocks). LDS = Al only (64x264 bf16 = 33.8 KB).
// Stage reads hacc as fp32 (scatter output) and converts to bf16.
// Layouts (HW-verified): A[m=lane&15][k=(lane>>4)*8+j];
//                        C/D col=lane&15, row=(lane>>4)*4+reg.
// ---------------------------------------------------------------------------
__global__ __launch_bounds__(256, 3) void mlp_fused(
    const float* __restrict__ hacc, const __hip_bfloat16* __restrict__ WdT,
    const __hip_bfloat16* __restrict__ WsT, const float* __restrict__ bs,
    float* __restrict__ out, int M)
{
    __shared__ __hip_bfloat16 Al[64][264];   // 256 cols + 8 pad

    int t = threadIdx.x;
    int lane = t & 63, w = t >> 6;
    int q = lane >> 4, r16 = lane & 15;
    int m0 = blockIdx.x * 64;

    // stage hacc tile (64 x 128 fp32) -> Al bf16 : 2048 float4 chunks
#pragma unroll
    for (int it = 0; it < 8; ++it) {
        int idx = it * 256 + t;
        int row = idx >> 5;              // 32 chunks / row
        int col = (idx & 31) * 4;
        int gr = m0 + row; if (gr >= M) gr = M - 1;
        float4 v = *(const float4*)&hacc[(long)gr * HIDDEN + col];
        Al[row][col + 0] = __float2bfloat16(v.x);
        Al[row][col + 1] = __float2bfloat16(v.y);
        Al[row][col + 2] = __float2bfloat16(v.z);
        Al[row][col + 3] = __float2bfloat16(v.w);
    }
    __syncthreads();

    for (int layer = 0; layer < 4; ++layer) {
        const int K = (layer == 0) ? 128 : 256;
        const __hip_bfloat16* BT = (layer == 0) ? WdT : WsT + (layer - 1) * 65536;
        const __hip_bfloat16* Brow = BT + (long)(w * 64 + r16) * K;

        floatx4 acc[4][4] = {};
        short8 bcur[4], bnxt[4];
#pragma unroll
        for (int nt = 0; nt < 4; ++nt)
            bcur[nt] = *(const short8*)&Brow[(long)nt * 16 * K + q * 8];

        for (int kk = 0; kk < K; kk += 32) {
            short8 af[4];
#pragma unroll
            for (int mt = 0; mt < 4; ++mt)
                af[mt] = *(const short8*)&Al[mt * 16 + r16][kk + q * 8];
            int kn = kk + 32;
            if (kn < K) {
#pragma unroll
                for (int nt = 0; nt < 4; ++nt)
                    bnxt[nt] = *(const short8*)&Brow[(long)nt * 16 * K + kn + q * 8];
            }
#pragma unroll
            for (int mt = 0; mt < 4; ++mt)
#pragma unroll
                for (int nt = 0; nt < 4; ++nt)
                    acc[mt][nt] = __builtin_amdgcn_mfma_f32_16x16x32_bf16(
                        af[mt], bcur[nt], acc[mt][nt], 0, 0, 0);
#pragma unroll
            for (int nt = 0; nt < 4; ++nt) bcur[nt] = bnxt[nt];
        }

        if (layer < 3) {
            __syncthreads();
            const float* bias = (layer == 0) ? nullptr : bs + (layer - 1) * 256;
#pragma unroll
            for (int mt = 0; mt < 4; ++mt) {
#pragma unroll
                for (int rr = 0; rr < 4; ++rr) {
                    int row = mt * 16 + q * 4 + rr;
#pragma unroll
                    for (int nt = 0; nt < 4; ++nt) {
                        int col = w * 64 + nt * 16 + r16;
                        float v = acc[mt][nt][rr];
                        if (layer > 0) { v += bias[col]; v = v / (1.f + __expf(-v)); }
                        Al[row][col] = __float2bfloat16(v);
                    }
                }
            }
            __syncthreads();
        } else {
            const float* bias = bs + 2 * 256;
#pragma unroll
            for (int mt = 0; mt < 4; ++mt) {
#pragma unroll
                for (int rr = 0; rr < 4; ++rr) {
                    int row = m0 + mt * 16 + q * 4 + rr;
                    if (row < M) {
#pragma unroll
                        for (int nt = 0; nt < 4; ++nt) {
                            int col = w * 64 + nt * 16 + r16;
                            float v = acc[mt][nt][rr] + bias[col];
                            v = v / (1.f + __expf(-v));
                            out[(long)row * NOUT + col] = v;
                        }
                    }
                }
            }
        }
    }
}

// ---------------------------------------------------------------------------
extern "C" void kernel_launch(void* const* d_in, const int* in_sizes, int n_in,
                              void* d_out, int out_size, void* d_ws, size_t ws_size,
                              hipStream_t stream)
{
    const float* x    = (const float*)d_in[0];
    const float* rbf  = (const float*)d_in[1];
    const int*   idx  = (const int*)d_in[2];
    const float* Wrbf = (const float*)d_in[3];
    const float* Wd   = (const float*)d_in[4];
    const float* Ws   = (const float*)d_in[5];
    const float* bs   = (const float*)d_in[6];

    int E = in_sizes[0] / HIDDEN;
    int M = out_size / NOUT;         // num_nodes

    char* ws = (char*)d_ws;
    float* hacc = (float*)ws;                                    // M*128 fp32
    size_t off = (size_t)M * HIDDEN * sizeof(float);
    __hip_bfloat16* WdT = (__hip_bfloat16*)(ws + off); off += 256 * 128 * 2;
    __hip_bfloat16* WsT = (__hip_bfloat16*)(ws + off); off += 3 * 256 * 256 * 2;

    hipMemsetAsync(hacc, 0, (size_t)M * HIDDEN * sizeof(float), stream);
    prep_weights<<<(256 * 128 + 3 * 256 * 256 + 255) / 256, 256, 0, stream>>>(Wd, Ws, WdT, WsT);
    scatter_k<<<2048, 256, 0, stream>>>(x, rbf, idx, Wrbf, hacc, E);
    mlp_fused<<<(M + 63) / 64, 256, 0, stream>>>(hacc, WdT, WsT, bs, (float*)d_out, M);
}

// Round 5
// 642.136 us; speedup vs baseline: 2.1714x; 1.4658x over previous
//
#include <hip/hip_runtime.h>
#include <hip/hip_bf16.h>
#include <cstdint>

typedef __attribute__((ext_vector_type(8))) short short8;
typedef __attribute__((ext_vector_type(4))) float floatx4;

#define HIDDEN 128
#define NOUT 256
#define CAP 128          // bucket capacity per node (mean degree 12; P(>128)~e^-180)
#define OVF_MAX 4096

// ---------------------------------------------------------------------------
// K1: zero counters + weight convert/transpose to bf16.
// WdT[n][k] = W_down[k][n] (256x128); WsT[l][n][k] = Ws[l][k][n] (3x256x256)
// ---------------------------------------------------------------------------
__global__ __launch_bounds__(256) void prep_k(
    const float* __restrict__ Wd, const float* __restrict__ Ws,
    __hip_bfloat16* __restrict__ WdT, __hip_bfloat16* __restrict__ WsT,
    int* __restrict__ cnt, int* __restrict__ ovf_cnt, int M)
{
    int tid = blockIdx.x * 256 + threadIdx.x;
    if (tid < M) cnt[tid] = 0;
    if (tid == 0) *ovf_cnt = 0;
    if (tid < 256 * 128) {
        int n = tid >> 7, k = tid & 127;
        WdT[tid] = __float2bfloat16(Wd[k * 256 + n]);
    }
    int tid2 = tid - 256 * 128;
    if (tid2 >= 0 && tid2 < 3 * 256 * 256) {
        int l = tid2 >> 16;
        int rem = tid2 & 65535;
        int n = rem >> 8, k = rem & 255;
        WsT[tid2] = __float2bfloat16(Ws[l * 65536 + k * 256 + n]);
    }
}

// ---------------------------------------------------------------------------
// K2: bucket fill. Replaces {hist, scan x3, fill} (5 dispatches) with ONE.
// pos = atomicAdd(cnt[node]); slots[node*CAP+pos] = e. Overflow (never in
// practice) goes to a small side list consumed by K3.
// ---------------------------------------------------------------------------
__global__ __launch_bounds__(256) void fill_k(
    const int* __restrict__ idx, int* __restrict__ cnt,
    int* __restrict__ slots, int* __restrict__ ovf_cnt,
    int* __restrict__ ovf, int E)
{
    int e = blockIdx.x * 256 + threadIdx.x;
    if (e >= E) return;
    int node = idx[e];
    int pos = atomicAdd(&cnt[node], 1);
    if (pos < CAP) {
        slots[(long)node * CAP + pos] = e;
    } else {
        int o = atomicAdd(ovf_cnt, 1);
        if (o < OVF_MAX) { ovf[2 * o] = node; ovf[2 * o + 1] = e; }
    }
}

// ---------------------------------------------------------------------------
// K3: fused gather + 4-layer MLP. Block owns 64 node-rows.
// Phase 1 (gather): wave w handles nodes w*16..w*16+15 sequentially; lane
// owns 2 hidden channels. Per node: one coalesced 64-wide eid load, then
// unroll-4 edge loop (4 independent 512B x-row loads in flight), fp32
// accumulate, write bf16 straight into the LDS A-tile. hacc never exists.
// Phase 2 (MLP): identical to the harness-verified mlp_fused (B from global
// with 1-deep register prefetch; weights L2-hot).
// Layouts (HW-verified): A[m=lane&15][k=(lane>>4)*8+j];
//                        C/D col=lane&15, row=(lane>>4)*4+reg.
// ---------------------------------------------------------------------------
__global__ __launch_bounds__(256, 2) void gather_mlp(
    const float* __restrict__ x, const float* __restrict__ rbf,
    const float* __restrict__ Wrbf, const int* __restrict__ cnt,
    const int* __restrict__ slots, const int* __restrict__ ovf_cnt,
    const int* __restrict__ ovf, const __hip_bfloat16* __restrict__ WdT,
    const __hip_bfloat16* __restrict__ WsT, const float* __restrict__ bs,
    float* __restrict__ out, int M)
{
    __shared__ __hip_bfloat16 Al[64][264];   // 256 cols + 8 pad

    int t = threadIdx.x;
    int lane = t & 63, w = t >> 6;
    int q = lane >> 4, r16 = lane & 15;
    int m0 = blockIdx.x * 64;
    int c0 = lane * 2;

    // ---- Phase 1: gather 64 rows into Al ----
    float w0[6], w1[6];
#pragma unroll
    for (int r = 0; r < 6; ++r) {
        w0[r] = Wrbf[r * HIDDEN + c0];
        w1[r] = Wrbf[r * HIDDEN + c0 + 1];
    }
    int nov = *ovf_cnt;   // uniform; ==0 in practice

    for (int i = 0; i < 16; ++i) {
        int n = m0 + w * 16 + i;
        float a0 = 0.f, a1 = 0.f;
        if (n < M) {
            int c = cnt[n]; if (c > CAP) c = CAP;
            for (int p = 0; p < c; p += 64) {
                int nbk = c - p; if (nbk > 64) nbk = 64;
                int eid = (p + lane < c) ? slots[(long)n * CAP + p + lane] : 0;
                int j = 0;
                for (; j + 4 <= nbk; j += 4) {
#pragma unroll
                    for (int u = 0; u < 4; ++u) {
                        int e = __builtin_amdgcn_readlane(eid, j + u);
                        const float* rb = rbf + (long)e * 6;
                        float2 xv = *(const float2*)&x[(long)e * HIDDEN + c0];
                        float p0 = 0.f, p1 = 0.f;
#pragma unroll
                        for (int r = 0; r < 6; ++r) {
                            float rv = rb[r];
                            p0 += rv * w0[r];
                            p1 += rv * w1[r];
                        }
                        a0 += p0 * xv.x;
                        a1 += p1 * xv.y;
                    }
                }
                for (; j < nbk; ++j) {
                    int e = __builtin_amdgcn_readlane(eid, j);
                    const float* rb = rbf + (long)e * 6;
                    float2 xv = *(const float2*)&x[(long)e * HIDDEN + c0];
                    float p0 = 0.f, p1 = 0.f;
#pragma unroll
                    for (int r = 0; r < 6; ++r) {
                        float rv = rb[r];
                        p0 += rv * w0[r];
                        p1 += rv * w1[r];
                    }
                    a0 += p0 * xv.x;
                    a1 += p1 * xv.y;
                }
            }
            if (nov > 0) {          // overflow rescue (cold path, never taken)
                int no = nov < OVF_MAX ? nov : OVF_MAX;
                for (int o = 0; o < no; ++o) {
                    if (ovf[2 * o] == n) {
                        int e = ovf[2 * o + 1];
                        const float* rb = rbf + (long)e * 6;
                        float2 xv = *(const float2*)&x[(long)e * HIDDEN + c0];
                        float p0 = 0.f, p1 = 0.f;
#pragma unroll
                        for (int r = 0; r < 6; ++r) {
                            float rv = rb[r];
                            p0 += rv * w0[r];
                            p1 += rv * w1[r];
                        }
                        a0 += p0 * xv.x;
                        a1 += p1 * xv.y;
                    }
                }
            }
        }
        int row = w * 16 + i;
        Al[row][c0]     = __float2bfloat16(a0);
        Al[row][c0 + 1] = __float2bfloat16(a1);
    }
    __syncthreads();

    // ---- Phase 2: 4-layer MLP (verified structure) ----
    for (int layer = 0; layer < 4; ++layer) {
        const int K = (layer == 0) ? 128 : 256;
        const __hip_bfloat16* BT = (layer == 0) ? WdT : WsT + (layer - 1) * 65536;
        const __hip_bfloat16* Brow = BT + (long)(w * 64 + r16) * K;

        floatx4 acc[4][4] = {};
        short8 bcur[4], bnxt[4];
#pragma unroll
        for (int nt = 0; nt < 4; ++nt)
            bcur[nt] = *(const short8*)&Brow[(long)nt * 16 * K + q * 8];

        for (int kk = 0; kk < K; kk += 32) {
            short8 af[4];
#pragma unroll
            for (int mt = 0; mt < 4; ++mt)
                af[mt] = *(const short8*)&Al[mt * 16 + r16][kk + q * 8];
            int kn = kk + 32;
            if (kn < K) {
#pragma unroll
                for (int nt = 0; nt < 4; ++nt)
                    bnxt[nt] = *(const short8*)&Brow[(long)nt * 16 * K + kn + q * 8];
            }
#pragma unroll
            for (int mt = 0; mt < 4; ++mt)
#pragma unroll
                for (int nt = 0; nt < 4; ++nt)
                    acc[mt][nt] = __builtin_amdgcn_mfma_f32_16x16x32_bf16(
                        af[mt], bcur[nt], acc[mt][nt], 0, 0, 0);
#pragma unroll
            for (int nt = 0; nt < 4; ++nt) bcur[nt] = bnxt[nt];
        }

        if (layer < 3) {
            __syncthreads();
            const float* bias = (layer == 0) ? nullptr : bs + (layer - 1) * 256;
#pragma unroll
            for (int mt = 0; mt < 4; ++mt) {
#pragma unroll
                for (int rr = 0; rr < 4; ++rr) {
                    int row = mt * 16 + q * 4 + rr;
#pragma unroll
                    for (int nt = 0; nt < 4; ++nt) {
                        int col = w * 64 + nt * 16 + r16;
                        float v = acc[mt][nt][rr];
                        if (layer > 0) { v += bias[col]; v = v / (1.f + __expf(-v)); }
                        Al[row][col] = __float2bfloat16(v);
                    }
                }
            }
            __syncthreads();
        } else {
            const float* bias = bs + 2 * 256;
#pragma unroll
            for (int mt = 0; mt < 4; ++mt) {
#pragma unroll
                for (int rr = 0; rr < 4; ++rr) {
                    int row = m0 + mt * 16 + q * 4 + rr;
                    if (row < M) {
#pragma unroll
                        for (int nt = 0; nt < 4; ++nt) {
                            int col = w * 64 + nt * 16 + r16;
                            float v = acc[mt][nt][rr] + bias[col];
                            v = v / (1.f + __expf(-v));
                            out[(long)row * NOUT + col] = v;
                        }
                    }
                }
            }
        }
    }
}

// ---------------------------------------------------------------------------
extern "C" void kernel_launch(void* const* d_in, const int* in_sizes, int n_in,
                              void* d_out, int out_size, void* d_ws, size_t ws_size,
                              hipStream_t stream)
{
    const float* x    = (const float*)d_in[0];
    const float* rbf  = (const float*)d_in[1];
    const int*   idx  = (const int*)d_in[2];
    const float* Wrbf = (const float*)d_in[3];
    const float* Wd   = (const float*)d_in[4];
    const float* Ws   = (const float*)d_in[5];
    const float* bs   = (const float*)d_in[6];

    int E = in_sizes[0] / HIDDEN;
    int M = out_size / NOUT;         // num_nodes

    char* ws = (char*)d_ws;
    int* slots   = (int*)ws;                         size_t off = (size_t)M * CAP * 4;
    int* cnt     = (int*)(ws + off);                 off += (size_t)M * 4;
    int* ovf_cnt = (int*)(ws + off);                 off += 256;
    int* ovf     = (int*)(ws + off);                 off += (size_t)OVF_MAX * 2 * 4;
    __hip_bfloat16* WdT = (__hip_bfloat16*)(ws + off); off += 256 * 128 * 2;
    __hip_bfloat16* WsT = (__hip_bfloat16*)(ws + off); off += 3 * 256 * 256 * 2;

    prep_k<<<896, 256, 0, stream>>>(Wd, Ws, WdT, WsT, cnt, ovf_cnt, M);
    fill_k<<<(E + 255) / 256, 256, 0, stream>>>(idx, cnt, slots, ovf_cnt, ovf, E);
    gather_mlp<<<(M + 63) / 64, 256, 0, stream>>>(
        x, rbf, Wrbf, cnt, slots, ovf_cnt, ovf, WdT, WsT, bs, (float*)d_out, M);
}